// Round 2
// baseline (529.109 us; speedup 1.0000x reference)
//
#include <hip/hip_runtime.h>

// L2_MSE_CLOZE: new_w[v] = count[v]>0 ? 0.5*w[v] + 0.5*mean(out rows with data==v & idx==1)
//                                     : w[v]
// Inverted-index gather formulation. S=131072, D=512, V=100000.

#define DIMS 512
#define CAP 16        // bucket capacity; Poisson(0.655) -> P(count>16) ~ 1e-15/row
#define OVF_CAP 4096  // exact fallback for overflow positions
#define VPW 4         // vocab rows per wave (MLP: 4 bucket + 8 row loads in flight)

// ---------------- K1: bucket fill (also produces final counts) ----------------
__global__ void l2cloze_fill_buckets(const int* __restrict__ data, const int* __restrict__ idxs,
                                     int S, int* __restrict__ counts, int* __restrict__ buckets,
                                     int* __restrict__ ovf_cnt, int* __restrict__ ovf_list) {
    int s = blockIdx.x * blockDim.x + threadIdx.x;
    if (s >= S) return;
    if (idxs[s] != 1) return;
    int v = data[s];
    int slot = atomicAdd(&counts[v], 1);
    if (slot < CAP) {
        buckets[v * CAP + slot] = s;
    } else {
        int o = atomicAdd(ovf_cnt, 1);
        if (o < OVF_CAP) ovf_list[o] = s;
    }
}

// ---------------- K2: gather + EMA, 4 vocab rows per wave, batched loads ----------------
__global__ __launch_bounds__(256, 4) void l2cloze_gather4(
        const float* __restrict__ outm,      // [S, D]
        const float* __restrict__ w,         // [V, D]
        const int* __restrict__ counts,      // [V]
        const int* __restrict__ buckets,     // [V, CAP]
        float* __restrict__ dst,             // [V, D]
        int V) {
    const int wave = threadIdx.x >> 6;
    const int lane = threadIdx.x & 63;
    const int v0 = (blockIdx.x * 4 + wave) * VPW;

    int c[VPW], kc[VPW];
    float4 a0[VPW], a1[VPW], s0[VPW], s1[VPW];

    // batched independent loads: counts then w-rows (8 float4 in flight)
    #pragma unroll
    for (int i = 0; i < VPW; ++i) {
        int v = v0 + i;
        c[i] = (v < V) ? counts[v] : 0;
    }
    #pragma unroll
    for (int i = 0; i < VPW; ++i) {
        int v = v0 + i;
        if (v < V) {
            const float4* wrow = (const float4*)(w + (size_t)v * DIMS);
            a0[i] = wrow[lane];
            a1[i] = wrow[lane + 64];
        }
    }

    int kcmax = 0;
    #pragma unroll
    for (int i = 0; i < VPW; ++i) {
        kc[i] = c[i] < CAP ? c[i] : CAP;
        kcmax = kc[i] > kcmax ? kc[i] : kcmax;
        s0[i] = make_float4(0.f, 0.f, 0.f, 0.f);
        s1[i] = make_float4(0.f, 0.f, 0.f, 0.f);
    }

    // k-outer / row-inner: per k, up to VPW bucket loads then 2*VPW row loads in flight
    #pragma unroll 1
    for (int k = 0; k < kcmax; ++k) {
        int sidx[VPW];
        #pragma unroll
        for (int i = 0; i < VPW; ++i)
            if (k < kc[i]) sidx[i] = buckets[(v0 + i) * CAP + k];   // uniform branch
        #pragma unroll
        for (int i = 0; i < VPW; ++i) {
            if (k < kc[i]) {
                const float4* r = (const float4*)(outm + (size_t)sidx[i] * DIMS);
                float4 b0 = r[lane];
                float4 b1 = r[lane + 64];
                s0[i].x += b0.x; s0[i].y += b0.y; s0[i].z += b0.z; s0[i].w += b0.w;
                s1[i].x += b1.x; s1[i].y += b1.y; s1[i].z += b1.z; s1[i].w += b1.w;
            }
        }
    }

    // finalize + store
    #pragma unroll
    for (int i = 0; i < VPW; ++i) {
        int v = v0 + i;
        if (v >= V) continue;
        float4* drow = (float4*)(dst + (size_t)v * DIMS);
        if (c[i] == 0) {
            drow[lane] = a0[i];
            drow[lane + 64] = a1[i];
        } else {
            float sc = 0.5f / (float)c[i];
            float4 r0, r1;
            r0.x = 0.5f * a0[i].x + sc * s0[i].x;  r0.y = 0.5f * a0[i].y + sc * s0[i].y;
            r0.z = 0.5f * a0[i].z + sc * s0[i].z;  r0.w = 0.5f * a0[i].w + sc * s0[i].w;
            r1.x = 0.5f * a1[i].x + sc * s1[i].x;  r1.y = 0.5f * a1[i].y + sc * s1[i].y;
            r1.z = 0.5f * a1[i].z + sc * s1[i].z;  r1.w = 0.5f * a1[i].w + sc * s1[i].w;
            drow[lane] = r0;
            drow[lane + 64] = r1;
        }
    }
}

// ---------------- K3: exact overflow fallback (normally 0 iterations) ----------------
__global__ void l2cloze_ovf_scatter(const float* __restrict__ outm, const int* __restrict__ data,
                                    const int* __restrict__ counts, const int* __restrict__ ovf_cnt,
                                    const int* __restrict__ ovf_list, float* __restrict__ dst) {
    int n = *ovf_cnt;
    if (n > OVF_CAP) n = OVF_CAP;
    const int lane = threadIdx.x & 63;
    const int waveGlobal = (blockIdx.x * blockDim.x + threadIdx.x) >> 6;
    const int nWaves = (gridDim.x * blockDim.x) >> 6;
    for (int i = waveGlobal; i < n; i += nWaves) {
        int s = ovf_list[i];
        int v = data[s];
        float sc = 0.5f / (float)counts[v];
        const float* r = outm + (size_t)s * DIMS + lane * 8;
        float* d = dst + (size_t)v * DIMS + lane * 8;
        #pragma unroll
        for (int j = 0; j < 8; ++j) atomicAdd(&d[j], sc * r[j]);
    }
}

extern "C" void kernel_launch(void* const* d_in, const int* in_sizes, int n_in,
                              void* d_out, int out_size, void* d_ws, size_t ws_size,
                              hipStream_t stream) {
    const float* outm  = (const float*)d_in[0];   // [S, D]
    const float* wgt   = (const float*)d_in[1];   // [V, D]
    const int*   data  = (const int*)d_in[2];     // [S]
    const int*   idxs  = (const int*)d_in[3];     // [S]
    float* dst = (float*)d_out;                   // [V, D]

    const int S = in_sizes[2];
    const int V = in_sizes[1] / DIMS;

    // workspace layout
    char* ws = (char*)d_ws;
    size_t off_counts  = 0;
    size_t off_ovfcnt  = (size_t)V * 4;
    size_t off_buckets = ((off_ovfcnt + 4 + 127) / 128) * 128;
    size_t off_ovflist = off_buckets + (size_t)V * CAP * 4;
    int* counts   = (int*)(ws + off_counts);
    int* ovf_cnt  = (int*)(ws + off_ovfcnt);
    int* buckets  = (int*)(ws + off_buckets);
    int* ovf_list = (int*)(ws + off_ovflist);

    // zero counts + overflow counter (ws re-poisoned 0xAA before every call)
    hipMemsetAsync(ws, 0, off_buckets, stream);

    // K1: inverted index
    l2cloze_fill_buckets<<<(S + 255) / 256, 256, 0, stream>>>(data, idxs, S, counts, buckets,
                                                              ovf_cnt, ovf_list);

    // K2: gather + EMA, 4 rows/wave, 16 rows/block
    l2cloze_gather4<<<(V + 4 * VPW - 1) / (4 * VPW), 256, 0, stream>>>(outm, wgt, counts,
                                                                       buckets, dst, V);

    // K3: exact overflow handling (expected no-op)
    l2cloze_ovf_scatter<<<16, 256, 0, stream>>>(outm, data, counts, ovf_cnt, ovf_list, dst);
}